// Round 5
// baseline (252.312 us; speedup 1.0000x reference)
//
#include <hip/hip_runtime.h>

typedef unsigned short u16;
typedef unsigned int   u32;
typedef __attribute__((ext_vector_type(8))) short bfrag;   // 8 x bf16
typedef __attribute__((ext_vector_type(4))) float ffrag;   // 4 x f32 acc

#define MFMA16(a,b,c) __builtin_amdgcn_mfma_f32_16x16x32_bf16((a),(b),(c),0,0,0)

// async global->LDS, 16B per lane; LDS dest = wave-uniform base + lane*16
#define GLL16(gp, lp) __builtin_amdgcn_global_load_lds( \
    (const __attribute__((address_space(1))) u32*)(gp), \
    (__attribute__((address_space(3))) u32*)(lp), 16, 0, 0)

__device__ __forceinline__ u16 f2b(float f) {          // fp32 -> bf16 RNE
  u32 u = __float_as_uint(f);
  return (u16)((u + 0x7fffu + ((u >> 16) & 1u)) >> 16);
}
__device__ __forceinline__ float b2f(u16 v) { return __uint_as_float(((u32)v) << 16); }

__device__ __forceinline__ void unpack8(uint4 q, u16 e[8]) {
  e[0] = q.x & 0xffffu; e[1] = q.x >> 16;
  e[2] = q.y & 0xffffu; e[3] = q.y >> 16;
  e[4] = q.z & 0xffffu; e[5] = q.z >> 16;
  e[6] = q.w & 0xffffu; e[7] = q.w >> 16;
}

// ---------------------------------------------------------------------------
// K0: fp32 -> bf16 conversion of x, Wk|Wv|Wr (stacked), Wo
// ---------------------------------------------------------------------------
__global__ __launch_bounds__(256) void cvt_all(
    const float* __restrict__ x,  const float* __restrict__ wk,
    const float* __restrict__ wv, const float* __restrict__ wr,
    const float* __restrict__ wo,
    u16* __restrict__ xb, u16* __restrict__ wb, u16* __restrict__ wob)
{
  size_t i4 = ((size_t)blockIdx.x * 256 + threadIdx.x) * 4;
  const float* src; u16* dst; size_t off;
  if      (i4 <  8388608) { src = x;  dst = xb;            off = i4; }
  else if (i4 <  9437184) { src = wk; dst = wb;            off = i4 - 8388608; }
  else if (i4 < 10485760) { src = wv; dst = wb + 1048576;  off = i4 - 9437184; }
  else if (i4 < 11534336) { src = wr; dst = wb + 2097152;  off = i4 - 10485760; }
  else                    { src = wo; dst = wob;           off = i4 - 11534336; }
  float4 f = *(const float4*)(src + off);
  u16 o[4] = { f2b(f.x), f2b(f.y), f2b(f.z), f2b(f.w) };
  *(ushort4*)(dst + off) = make_ushort4(o[0], o[1], o[2], o[3]);
}

// ---------------------------------------------------------------------------
// K1: fused k/v/r projection. M=8192, N=3072, K=1024.
// Block tile 128x256, 256 threads = 4 waves in 2x2; WAVE TILE 64x128
// (acc 4x8): A-frags read once, reused over 8 B-frags -> 12 b128 / 32 MFMA
// = 25% less LDS-read traffic per FLOP than 64x64 (which was the binding
// pipe per round-4 counters). BK=32 dbuf (48KB), GLL16 staging.
// __launch_bounds__(256,2): cap 256 VGPR (acc 128 + frags 48 + temps).
// XCD m-window swizzle: 8 m-tiles (2MB A) per XCD x 12 n-tiles, m fastest.
// ---------------------------------------------------------------------------
__global__ __launch_bounds__(256, 2) void k1_proj(
    const u16* __restrict__ xb, const u16* __restrict__ wb,
    const float* __restrict__ tf,
    u16* __restrict__ kws, u16* __restrict__ vws, u16* __restrict__ rws)
{
  __shared__ u16 As[2][128 * 32];
  __shared__ u16 Bs[2][256 * 32];
  const int tid  = threadIdx.x;
  const int wave = tid >> 6, lane = tid & 63;
  const int li = lane & 15, quad = lane >> 4;
  const int wm = (wave >> 1) * 64;     // wave row offset in 128
  const int wn = (wave & 1) * 128;     // wave col offset in 256

  const int bid = blockIdx.x;
  const int xcd = bid & 7, j = bid >> 3;            // j in [0,96)
  const int n0 = (j >> 3) * 256;                    // 12 n-tiles of 256
  const int m0 = ((xcd << 3) | (j & 7)) * 128;      // 8 m-tiles per XCD

  ffrag acc[4][8];
#pragma unroll
  for (int i = 0; i < 4; ++i)
#pragma unroll
    for (int jj = 0; jj < 8; ++jj)
#pragma unroll
      for (int r = 0; r < 4; ++r) acc[i][jj][r] = 0.f;

  // staging: each GLL16 round covers 16 rows (4 lanes/row, 8 bf16 each)
  const int sr = lane >> 2, sc = (lane & 3) * 8;
  const u16* ga0 = xb + (size_t)(m0 + wave * 32 + sr) * 1024 + sc;   // A: 2 rounds
  const u16* gb0 = wb + (size_t)(n0 + wave * 64 + sr) * 1024 + sc;   // B: 4 rounds

  GLL16(ga0,             As[0] + wave * 1024);
  GLL16(ga0 + 16 * 1024, As[0] + wave * 1024 + 512);
  GLL16(gb0,             Bs[0] + wave * 2048);
  GLL16(gb0 + 16 * 1024, Bs[0] + wave * 2048 + 512);
  GLL16(gb0 + 32 * 1024, Bs[0] + wave * 2048 + 1024);
  GLL16(gb0 + 48 * 1024, Bs[0] + wave * 2048 + 1536);

  for (int it = 0; it < 32; ++it) {
    __syncthreads();   // drains stage(it) loads; frees other buffer
    if (it + 1 < 32) {
      const int nb = (it + 1) & 1;
      const u16* ga = ga0 + (it + 1) * 32;
      const u16* gb = gb0 + (it + 1) * 32;
      GLL16(ga,             As[nb] + wave * 1024);
      GLL16(ga + 16 * 1024, As[nb] + wave * 1024 + 512);
      GLL16(gb,             Bs[nb] + wave * 2048);
      GLL16(gb + 16 * 1024, Bs[nb] + wave * 2048 + 512);
      GLL16(gb + 32 * 1024, Bs[nb] + wave * 2048 + 1024);
      GLL16(gb + 48 * 1024, Bs[nb] + wave * 2048 + 1536);
    }
    const int cb = it & 1;
    bfrag av[4], bv[8];
#pragma unroll
    for (int i = 0; i < 4; ++i)  av[i]  = *(const bfrag*)&As[cb][(wm + i * 16 + li) * 32 + quad * 8];
#pragma unroll
    for (int jj = 0; jj < 8; ++jj) bv[jj] = *(const bfrag*)&Bs[cb][(wn + jj * 16 + li) * 32 + quad * 8];
#pragma unroll
    for (int i = 0; i < 4; ++i)
#pragma unroll
      for (int jj = 0; jj < 8; ++jj)
        acc[i][jj] = MFMA16(av[i], bv[jj], acc[i][jj]);
  }

  const int sel = n0 >> 10;   // uniform per block (256 | 1024)
#pragma unroll
  for (int i = 0; i < 4; ++i) {
#pragma unroll
    for (int jj = 0; jj < 8; ++jj) {
#pragma unroll
      for (int r = 0; r < 4; ++r) {
        int m = m0 + wm + i * 16 + quad * 4 + r;       // row = b*2048 + l
        int n = n0 + wn + jj * 16 + li;
        int c = n & 1023;                               // h*64 + d
        int bb = m >> 11, l = m & 2047;
        size_t dst = (size_t)((bb << 4) | (c >> 6)) * 131072 + (size_t)l * 64 + (c & 63);
        float v = acc[i][jj][r];
        if (sel == 0)      kws[dst] = f2b(v * tf[c]);                 // fold time_first into k
        else if (sel == 1) vws[dst] = f2b(v);
        else               rws[dst] = f2b(1.f / (1.f + __expf(-v)));  // sigmoid
      }
    }
  }
}

// ---------------------------------------------------------------------------
// RWKV chunked recurrence, de-serialized into 3 parallel kernels.
// K2a: per (b,h,chunk) block, U^T[e][d] = sum_s V[s,e] * Ktf[s,d]*Dh^(63-s)
// K2b: scan S_{c+1} = Dh^64 S_c + U_c (fp32), store S^T per chunk (bf16)
// K2c: Y = masked(R@Ktf^T)@V + Dh^(t+1) * (R @ S_c^T)
// ---------------------------------------------------------------------------
#define ST 72

__global__ __launch_bounds__(256) void k2a_u(
    const u16* __restrict__ kws, const u16* __restrict__ vws,
    const float* __restrict__ td, float* __restrict__ ut)
{
  __shared__ u16 KbarT[64 * ST];  // [d][s], scaled by Dh^(63-s)
  __shared__ u16 Vt[64 * ST];     // [e][s]
  const int tid = threadIdx.x;
  const int lane = tid & 63, wave = tid >> 6;
  const int li = lane & 15, quad = lane >> 4;
  const int wr = (wave >> 1) * 32, wc = (wave & 1) * 32;
  const int bid = blockIdx.x;
  const int bh = bid >> 5, ch = bid & 31;
  const int h = bh & 15;
  const float l2D = log2f(td[h * 64]);
  const size_t base = (size_t)bh * 131072 + (size_t)ch * 4096;

#pragma unroll
  for (int it = 0; it < 2; ++it) {
    int c16 = tid + it * 256;
    int row = c16 >> 3, c8 = (c16 & 7) * 8;
    size_t g = base + (size_t)row * 64 + c8;
    uint4 kq = *(const uint4*)(kws + g);
    u16 ke[8]; unpack8(kq, ke);
    float sk = exp2f((float)(63 - row) * l2D);
#pragma unroll
    for (int jj = 0; jj < 8; ++jj) KbarT[(c8 + jj) * ST + row] = f2b(b2f(ke[jj]) * sk);
    uint4 vq = *(const uint4*)(vws + g);
    u16 ve[8]; unpack8(vq, ve);
#pragma unroll
    for (int jj = 0; jj < 8; ++jj) Vt[(c8 + jj) * ST + row] = ve[jj];
  }
  __syncthreads();

  ffrag U[2][2];
#pragma unroll
  for (int a = 0; a < 2; ++a)
#pragma unroll
    for (int b = 0; b < 2; ++b)
#pragma unroll
      for (int r = 0; r < 4; ++r) U[a][b][r] = 0.f;
#pragma unroll
  for (int kk = 0; kk < 64; kk += 32) {
    bfrag a0 = *(const bfrag*)&Vt[(wr + li) * ST + kk + quad * 8];
    bfrag a1 = *(const bfrag*)&Vt[(wr + 16 + li) * ST + kk + quad * 8];
    bfrag b0 = *(const bfrag*)&KbarT[(wc + li) * ST + kk + quad * 8];
    bfrag b1 = *(const bfrag*)&KbarT[(wc + 16 + li) * ST + kk + quad * 8];
    U[0][0] = MFMA16(a0, b0, U[0][0]);
    U[0][1] = MFMA16(a0, b1, U[0][1]);
    U[1][0] = MFMA16(a1, b0, U[1][0]);
    U[1][1] = MFMA16(a1, b1, U[1][1]);
  }

  float* dst = ut + ((size_t)bid << 12);   // [bh][ch][e][d]
#pragma unroll
  for (int ti = 0; ti < 2; ++ti)
#pragma unroll
    for (int tj = 0; tj < 2; ++tj)
#pragma unroll
      for (int r = 0; r < 4; ++r) {
        int e = wr + ti * 16 + quad * 4 + r;
        int d = wc + tj * 16 + li;
        dst[e * 64 + d] = U[ti][tj][r];
      }
}

__global__ __launch_bounds__(256) void k2b_scan(
    const float* __restrict__ ut, const float* __restrict__ td,
    u16* __restrict__ sbf, float* __restrict__ fstate)
{
  __shared__ float Sl[4 * 65];
  const int tid = threadIdx.x;
  const int bid = blockIdx.x;
  const int bh = bid >> 4, q = bid & 15;       // q: which 256-slice of ed
  const int ed = q * 256 + tid;                // ed = e*64 + d (transposed layout)
  const int h = bh & 15;
  const float Dh = td[h * 64];
  const float DhC = exp2f(64.f * log2f(Dh));

  float S = 0.f;
  size_t idx = ((size_t)bh * 32) * 4096 + ed;
  for (int c = 0; c < 32; ++c, idx += 4096) {
    sbf[idx] = f2b(S);             // state at START of chunk c
    S = S * DhC + ut[idx];
  }
  // final state: transpose [e][d] -> [d][e] via LDS
  Sl[(tid >> 6) * 65 + (tid & 63)] = S;   // e = q*4 + (tid>>6), d = tid&63
  __syncthreads();
  int d = tid >> 2, el = tid & 3;
  fstate[(size_t)bh * 4096 + (size_t)d * 64 + q * 4 + el] = Sl[el * 65 + d];
}

__global__ __launch_bounds__(256) void k2c_y(
    const u16* __restrict__ kws, const u16* __restrict__ vws, const u16* __restrict__ rws,
    const u16* __restrict__ sbf, const float* __restrict__ td,
    u16* __restrict__ yws)
{
  __shared__ u16 Rc[64 * ST];     // R natural [t][d]
  __shared__ u16 KcA[64 * ST];    // Ktf natural [s][d]; reused as Abuf [t][s]
  __shared__ u16 Vt[64 * ST];     // V^T [e][s]
  __shared__ u16 STc[64 * ST];    // S^T chunk [e][d]
  __shared__ float Dpow[65];

  const int tid = threadIdx.x;
  const int lane = tid & 63, wave = tid >> 6;
  const int li = lane & 15, quad = lane >> 4;
  const int wr = (wave >> 1) * 32, wc = (wave & 1) * 32;
  const int bid = blockIdx.x;
  const int bh = bid >> 5, ch = bid & 31;
  const int h = bh & 15, bb = bh >> 4;
  const float l2D = log2f(td[h * 64]);
  if (tid <= 64) Dpow[tid] = exp2f((float)tid * l2D);

  const size_t base = (size_t)bh * 131072 + (size_t)ch * 4096;
  const u16* sp = sbf + ((size_t)bid << 12);

#pragma unroll
  for (int it = 0; it < 2; ++it) {
    int c16 = tid + it * 256;
    int row = c16 >> 3, c8 = (c16 & 7) * 8;
    size_t g = base + (size_t)row * 64 + c8;
    *(uint4*)&Rc[row * ST + c8]  = *(const uint4*)(rws + g);
    *(uint4*)&KcA[row * ST + c8] = *(const uint4*)(kws + g);
    *(uint4*)&STc[row * ST + c8] = *(const uint4*)(sp + (size_t)row * 64 + c8);
    uint4 vq = *(const uint4*)(vws + g);
    u16 ve[8]; unpack8(vq, ve);
#pragma unroll
    for (int jj = 0; jj < 8; ++jj) Vt[(c8 + jj) * ST + row] = ve[jj];
  }
  __syncthreads();   // B1

  ffrag P[2][2], Y[2][2];
#pragma unroll
  for (int a = 0; a < 2; ++a)
#pragma unroll
    for (int b = 0; b < 2; ++b)
#pragma unroll
      for (int r = 0; r < 4; ++r) { P[a][b][r] = 0.f; Y[a][b][r] = 0.f; }

#pragma unroll
  for (int kk = 0; kk < 64; kk += 32) {
    bfrag a0 = *(const bfrag*)&Rc[(wr + li) * ST + kk + quad * 8];
    bfrag a1 = *(const bfrag*)&Rc[(wr + 16 + li) * ST + kk + quad * 8];
    bfrag b0 = *(const bfrag*)&KcA[(wc + li) * ST + kk + quad * 8];
    bfrag b1 = *(const bfrag*)&KcA[(wc + 16 + li) * ST + kk + quad * 8];
    P[0][0] = MFMA16(a0, b0, P[0][0]);
    P[0][1] = MFMA16(a0, b1, P[0][1]);
    P[1][0] = MFMA16(a1, b0, P[1][0]);
    P[1][1] = MFMA16(a1, b1, P[1][1]);
    bfrag s0 = *(const bfrag*)&STc[(wc + li) * ST + kk + quad * 8];
    bfrag s1 = *(const bfrag*)&STc[(wc + 16 + li) * ST + kk + quad * 8];
    Y[0][0] = MFMA16(a0, s0, Y[0][0]);
    Y[0][1] = MFMA16(a0, s1, Y[0][1]);
    Y[1][0] = MFMA16(a1, s0, Y[1][0]);
    Y[1][1] = MFMA16(a1, s1, Y[1][1]);
  }

  // row-scale the R@S^T partial by Dh^(t+1) (commutes: scale is per output row)
#pragma unroll
  for (int ti = 0; ti < 2; ++ti)
#pragma unroll
    for (int tj = 0; tj < 2; ++tj)
#pragma unroll
      for (int r = 0; r < 4; ++r) {
        int t = wr + ti * 16 + quad * 4 + r;
        Y[ti][tj][r] *= Dpow[t + 1];
      }
  __syncthreads();   // Bmid: everyone done reading KcA (Ktf)

  // masked decay-scaled A -> Abuf (aliases KcA)
#pragma unroll
  for (int ti = 0; ti < 2; ++ti)
#pragma unroll
    for (int tj = 0; tj < 2; ++tj)
#pragma unroll
      for (int r = 0; r < 4; ++r) {
        int t = wr + ti * 16 + quad * 4 + r;
        int s = wc + tj * 16 + li;
        float v = (t >= s) ? P[ti][tj][r] * Dpow[t - s] : 0.f;
        KcA[t * ST + s] = f2b(v);
      }
  __syncthreads();   // B2: Abuf visible

#pragma unroll
  for (int kk = 0; kk < 64; kk += 32) {
    bfrag aa0 = *(const bfrag*)&KcA[(wr + li) * ST + kk + quad * 8];
    bfrag aa1 = *(const bfrag*)&KcA[(wr + 16 + li) * ST + kk + quad * 8];
    bfrag vb0 = *(const bfrag*)&Vt[(wc + li) * ST + kk + quad * 8];
    bfrag vb1 = *(const bfrag*)&Vt[(wc + 16 + li) * ST + kk + quad * 8];
    Y[0][0] = MFMA16(aa0, vb0, Y[0][0]);
    Y[0][1] = MFMA16(aa0, vb1, Y[0][1]);
    Y[1][0] = MFMA16(aa1, vb0, Y[1][0]);
    Y[1][1] = MFMA16(aa1, vb1, Y[1][1]);
  }

#pragma unroll
  for (int ti = 0; ti < 2; ++ti)
#pragma unroll
    for (int tj = 0; tj < 2; ++tj)
#pragma unroll
      for (int r = 0; r < 4; ++r) {
        int t = wr + ti * 16 + quad * 4 + r;
        int e = wc + tj * 16 + li;
        yws[((size_t)(bb * 2048 + ch * 64 + t)) * 1024 + h * 64 + e] = f2b(Y[ti][tj][r]);
      }
}

// ---------------------------------------------------------------------------
// K3: y = Y_rwkv @ Wo^T, M=8192, N=1024, K=1024. Pipelined BK=32 dbuf
// + XCD m-window swizzle (8 m-tiles per XCD, n slow). 512 blocks = 2/CU.
// ---------------------------------------------------------------------------
__global__ __launch_bounds__(256) void k3_out(
    const u16* __restrict__ yb, const u16* __restrict__ wob, float* __restrict__ out)
{
  __shared__ u16 As[2][128 * 32];
  __shared__ u16 Bs[2][128 * 32];
  const int tid  = threadIdx.x;
  const int wave = tid >> 6, lane = tid & 63;
  const int li = lane & 15, quad = lane >> 4;
  const int wr = (wave >> 1) * 64, wc = (wave & 1) * 64;
  const int bid = blockIdx.x;
  const int xcd = bid & 7, j = bid >> 3;            // j in [0,64)
  const int n0 = (j >> 3) * 128;                    // 8 n-tiles
  const int m0 = ((xcd << 3) | (j & 7)) * 128;      // 8 m-tiles per XCD

  ffrag acc[4][4];
#pragma unroll
  for (int i = 0; i < 4; ++i)
#pragma unroll
    for (int jj = 0; jj < 4; ++jj)
#pragma unroll
      for (int r = 0; r < 4; ++r) acc[i][jj][r] = 0.f;

  const int srow = wave * 16 + (lane >> 2);
  const int scol = (lane & 3) * 8;
  const u16* ga0 = yb  + (size_t)(m0 + srow) * 1024 + scol;
  const u16* gb0 = wob + (size_t)(n0 + srow) * 1024 + scol;

  GLL16(ga0,             As[0] + wave * 512);
  GLL16(ga0 + 64 * 1024, As[0] + 2048 + wave * 512);
  GLL16(gb0,             Bs[0] + wave * 512);
  GLL16(gb0 + 64 * 1024, Bs[0] + 2048 + wave * 512);

  for (int it = 0; it < 32; ++it) {
    __syncthreads();
    if (it + 1 < 32) {
      const int nb = (it + 1) & 1;
      const u16* ga = ga0 + (it + 1) * 32;
      const u16* gb = gb0 + (it + 1) * 32;
      GLL16(ga,             As[nb] + wave * 512);
      GLL16(ga + 64 * 1024, As[nb] + 2048 + wave * 512);
      GLL16(gb,             Bs[nb] + wave * 512);
      GLL16(gb + 64 * 1024, Bs[nb] + 2048 + wave * 512);
    }
    const int cb = it & 1;
    bfrag av[4], bv[4];
#pragma unroll
    for (int i = 0; i < 4; ++i) av[i] = *(const bfrag*)&As[cb][(wr + i * 16 + li) * 32 + quad * 8];
#pragma unroll
    for (int jj = 0; jj < 4; ++jj) bv[jj] = *(const bfrag*)&Bs[cb][(wc + jj * 16 + li) * 32 + quad * 8];
#pragma unroll
    for (int i = 0; i < 4; ++i)
#pragma unroll
      for (int jj = 0; jj < 4; ++jj)
        acc[i][jj] = MFMA16(av[i], bv[jj], acc[i][jj]);
  }

#pragma unroll
  for (int i = 0; i < 4; ++i)
#pragma unroll
    for (int jj = 0; jj < 4; ++jj)
#pragma unroll
      for (int r = 0; r < 4; ++r) {
        int m = m0 + wr + i * 16 + quad * 4 + r;
        int n = n0 + wc + jj * 16 + li;
        out[(size_t)m * 1024 + n] = acc[i][jj][r];
      }
}

// ---------------------------------------------------------------------------
// Workspace layout (u16 elements):
//   xb   @ 0          (8388608)   -- reused as yws after K1
//   wb   @ 8388608    (3145728)
//   wob  @ 11534336   (1048576)
//   kws  @ 12582912   (8388608)   (B,H,L,HD) k*tf
//   vws  @ 20971520   (8388608)
//   rws  @ 29360128   (8388608)   sigmoid applied
//   ut   @ 37748736   (8388608 fp32 = 16777216 u16)  U^T per (bh,chunk)
//   sbf  @ 54525952   (8388608)   S^T per (bh,chunk), bf16
// total 125829120 bytes
// ---------------------------------------------------------------------------
extern "C" void kernel_launch(void* const* d_in, const int* in_sizes, int n_in,
                              void* d_out, int out_size, void* d_ws, size_t ws_size,
                              hipStream_t stream) {
  const float* x  = (const float*)d_in[0];
  const float* Wk = (const float*)d_in[1];
  const float* Wv = (const float*)d_in[2];
  const float* Wr = (const float*)d_in[3];
  const float* Wo = (const float*)d_in[4];
  const float* td = (const float*)d_in[5];
  const float* tf = (const float*)d_in[6];
  float* out = (float*)d_out;

  u16* ws  = (u16*)d_ws;
  u16* xb  = ws;
  u16* wb  = ws + 8388608;
  u16* wob = ws + 11534336;
  u16* kws = ws + 12582912;
  u16* vws = ws + 20971520;
  u16* rws = ws + 29360128;
  float* ut  = (float*)(ws + 37748736);
  u16*   sbf = ws + 54525952;
  u16* yws = xb;   // xb dead after K1

  hipLaunchKernelGGL(cvt_all, dim3(12288), dim3(256), 0, stream,
                     x, Wk, Wv, Wr, Wo, xb, wb, wob);
  hipLaunchKernelGGL(k1_proj, dim3(768), dim3(256), 0, stream,
                     xb, wb, tf, kws, vws, rws);
  hipLaunchKernelGGL(k2a_u, dim3(2048), dim3(256), 0, stream,
                     kws, vws, td, ut);
  hipLaunchKernelGGL(k2b_scan, dim3(1024), dim3(256), 0, stream,
                     ut, td, sbf, out + 8388608);
  hipLaunchKernelGGL(k2c_y, dim3(2048), dim3(256), 0, stream,
                     kws, vws, rws, sbf, td, yws);
  hipLaunchKernelGGL(k3_out, dim3(512), dim3(256), 0, stream,
                     yws, wob, out);
}

// Round 6
// 237.043 us; speedup vs baseline: 1.0644x; 1.0644x over previous
//
#include <hip/hip_runtime.h>

typedef unsigned short u16;
typedef unsigned int   u32;
typedef __attribute__((ext_vector_type(8))) short bfrag;   // 8 x bf16
typedef __attribute__((ext_vector_type(4))) float ffrag;   // 4 x f32 acc

#define MFMA16(a,b,c) __builtin_amdgcn_mfma_f32_16x16x32_bf16((a),(b),(c),0,0,0)

// async global->LDS, 16B per lane; LDS dest = wave-uniform base + lane*16
#define GLL16(gp, lp) __builtin_amdgcn_global_load_lds( \
    (const __attribute__((address_space(1))) u32*)(gp), \
    (__attribute__((address_space(3))) u32*)(lp), 16, 0, 0)

__device__ __forceinline__ u16 f2b(float f) {          // fp32 -> bf16 RNE
  u32 u = __float_as_uint(f);
  return (u16)((u + 0x7fffu + ((u >> 16) & 1u)) >> 16);
}
__device__ __forceinline__ float b2f(u16 v) { return __uint_as_float(((u32)v) << 16); }

__device__ __forceinline__ void unpack8(uint4 q, u16 e[8]) {
  e[0] = q.x & 0xffffu; e[1] = q.x >> 16;
  e[2] = q.y & 0xffffu; e[3] = q.y >> 16;
  e[4] = q.z & 0xffffu; e[5] = q.z >> 16;
  e[6] = q.w & 0xffffu; e[7] = q.w >> 16;
}

// ---------------------------------------------------------------------------
// K0: fp32 -> bf16 conversion of x, Wk|Wv|Wr (stacked), Wo
// ---------------------------------------------------------------------------
__global__ __launch_bounds__(256) void cvt_all(
    const float* __restrict__ x,  const float* __restrict__ wk,
    const float* __restrict__ wv, const float* __restrict__ wr,
    const float* __restrict__ wo,
    u16* __restrict__ xb, u16* __restrict__ wb, u16* __restrict__ wob)
{
  size_t i4 = ((size_t)blockIdx.x * 256 + threadIdx.x) * 4;
  const float* src; u16* dst; size_t off;
  if      (i4 <  8388608) { src = x;  dst = xb;            off = i4; }
  else if (i4 <  9437184) { src = wk; dst = wb;            off = i4 - 8388608; }
  else if (i4 < 10485760) { src = wv; dst = wb + 1048576;  off = i4 - 9437184; }
  else if (i4 < 11534336) { src = wr; dst = wb + 2097152;  off = i4 - 10485760; }
  else                    { src = wo; dst = wob;           off = i4 - 11534336; }
  float4 f = *(const float4*)(src + off);
  u16 o[4] = { f2b(f.x), f2b(f.y), f2b(f.z), f2b(f.w) };
  *(ushort4*)(dst + off) = make_ushort4(o[0], o[1], o[2], o[3]);
}

// ---------------------------------------------------------------------------
// K1: fused k/v/r projection. M=8192, N=3072, K=1024.
// ROUND-4 PROVEN CONFIG (81us): macro-tile BM=256 x BN=128, 512 threads
// (8 waves, 64x64 each, acc 4x4). BK=32 dbuf (48KB), GLL16 staging.
// 16 resident waves/CU hide the per-iter vmcnt drain (r5 showed 4-wave
// blocks with bigger wave-tiles regress: residency, not LDS BW, binds).
// XCD m-window swizzle: 4 m-tiles (2MB A) per XCD x all 24 n, m fastest.
// ---------------------------------------------------------------------------
__global__ __launch_bounds__(512, 4) void k1_proj(
    const u16* __restrict__ xb, const u16* __restrict__ wb,
    const float* __restrict__ tf,
    u16* __restrict__ kws, u16* __restrict__ vws, u16* __restrict__ rws)
{
  __shared__ u16 As[2][256 * 32];
  __shared__ u16 Bs[2][128 * 32];
  const int tid  = threadIdx.x;
  const int wave = tid >> 6, lane = tid & 63;
  const int li = lane & 15, quad = lane >> 4;
  const int wm = (wave >> 1) * 64, wn = (wave & 1) * 64;

  const int bid = blockIdx.x;
  const int xcd = bid & 7, j = bid >> 3;            // j in [0,96)
  const int n0 = (j >> 2) * 128;                    // 24 n-tiles
  const int m0 = ((xcd << 2) | (j & 3)) * 256;      // 4 m-tiles per XCD

  ffrag acc[4][4];
#pragma unroll
  for (int i = 0; i < 4; ++i)
#pragma unroll
    for (int jj = 0; jj < 4; ++jj)
#pragma unroll
      for (int r = 0; r < 4; ++r) acc[i][jj][r] = 0.f;

  // staging: A rows wave*32 + {0,16} + (lane>>2); B rows wave*16 + (lane>>2)
  const int sr = lane >> 2, sc = (lane & 3) * 8;
  const u16* ga0 = xb + (size_t)(m0 + wave * 32 + sr) * 1024 + sc;
  const u16* gb0 = wb + (size_t)(n0 + wave * 16 + sr) * 1024 + sc;

  GLL16(ga0,             As[0] + wave * 1024);
  GLL16(ga0 + 16 * 1024, As[0] + wave * 1024 + 512);
  GLL16(gb0,             Bs[0] + wave * 512);

  for (int it = 0; it < 32; ++it) {
    __syncthreads();   // drains stage(it) loads; frees other buffer
    if (it + 1 < 32) {
      const int nb = (it + 1) & 1;
      const u16* ga = ga0 + (it + 1) * 32;
      const u16* gb = gb0 + (it + 1) * 32;
      GLL16(ga,             As[nb] + wave * 1024);
      GLL16(ga + 16 * 1024, As[nb] + wave * 1024 + 512);
      GLL16(gb,             Bs[nb] + wave * 512);
    }
    const int cb = it & 1;
    bfrag av[4], bv[4];
#pragma unroll
    for (int i = 0; i < 4; ++i)  av[i]  = *(const bfrag*)&As[cb][(wm + i * 16 + li) * 32 + quad * 8];
#pragma unroll
    for (int jj = 0; jj < 4; ++jj) bv[jj] = *(const bfrag*)&Bs[cb][(wn + jj * 16 + li) * 32 + quad * 8];
#pragma unroll
    for (int i = 0; i < 4; ++i)
#pragma unroll
      for (int jj = 0; jj < 4; ++jj)
        acc[i][jj] = MFMA16(av[i], bv[jj], acc[i][jj]);
  }

  const int sel = n0 >> 10;   // uniform per block
#pragma unroll
  for (int i = 0; i < 4; ++i) {
#pragma unroll
    for (int jj = 0; jj < 4; ++jj) {
#pragma unroll
      for (int r = 0; r < 4; ++r) {
        int m = m0 + wm + i * 16 + quad * 4 + r;       // row = b*2048 + l
        int n = n0 + wn + jj * 16 + li;
        int c = n & 1023;                               // h*64 + d
        int bb = m >> 11, l = m & 2047;
        size_t dst = (size_t)((bb << 4) | (c >> 6)) * 131072 + (size_t)l * 64 + (c & 63);
        float v = acc[i][jj][r];
        if (sel == 0)      kws[dst] = f2b(v * tf[c]);                 // fold time_first into k
        else if (sel == 1) vws[dst] = f2b(v);
        else               rws[dst] = f2b(1.f / (1.f + __expf(-v)));  // sigmoid
      }
    }
  }
}

// ---------------------------------------------------------------------------
// RWKV chunked recurrence, de-serialized into 3 parallel kernels.
// K2a: per (b,h,chunk) block, U^T[e][d] = sum_s V[s,e] * Ktf[s,d]*Dh^(63-s)
//      (stored bf16: cross-chunk term is Dh^64-damped, error negligible)
// K2b: scan S_{c+1} = Dh^64 S_c + U_c (fp32 acc), store S^T per chunk (bf16)
// K2c: Y = masked(R@Ktf^T)@V + Dh^(t+1) * (R @ S_c^T)
// ---------------------------------------------------------------------------
#define ST 72

__global__ __launch_bounds__(256) void k2a_u(
    const u16* __restrict__ kws, const u16* __restrict__ vws,
    const float* __restrict__ td, u16* __restrict__ ut)
{
  __shared__ u16 KbarT[64 * ST];  // [d][s], scaled by Dh^(63-s)
  __shared__ u16 Vt[64 * ST];     // [e][s]
  const int tid = threadIdx.x;
  const int lane = tid & 63, wave = tid >> 6;
  const int li = lane & 15, quad = lane >> 4;
  const int wr = (wave >> 1) * 32, wc = (wave & 1) * 32;
  const int bid = blockIdx.x;
  const int bh = bid >> 5, ch = bid & 31;
  const int h = bh & 15;
  const float l2D = log2f(td[h * 64]);
  const size_t base = (size_t)bh * 131072 + (size_t)ch * 4096;

#pragma unroll
  for (int it = 0; it < 2; ++it) {
    int c16 = tid + it * 256;
    int row = c16 >> 3, c8 = (c16 & 7) * 8;
    size_t g = base + (size_t)row * 64 + c8;
    uint4 kq = *(const uint4*)(kws + g);
    u16 ke[8]; unpack8(kq, ke);
    float sk = exp2f((float)(63 - row) * l2D);
#pragma unroll
    for (int jj = 0; jj < 8; ++jj) KbarT[(c8 + jj) * ST + row] = f2b(b2f(ke[jj]) * sk);
    uint4 vq = *(const uint4*)(vws + g);
    u16 ve[8]; unpack8(vq, ve);
#pragma unroll
    for (int jj = 0; jj < 8; ++jj) Vt[(c8 + jj) * ST + row] = ve[jj];
  }
  __syncthreads();

  ffrag U[2][2];
#pragma unroll
  for (int a = 0; a < 2; ++a)
#pragma unroll
    for (int b = 0; b < 2; ++b)
#pragma unroll
      for (int r = 0; r < 4; ++r) U[a][b][r] = 0.f;
#pragma unroll
  for (int kk = 0; kk < 64; kk += 32) {
    bfrag a0 = *(const bfrag*)&Vt[(wr + li) * ST + kk + quad * 8];
    bfrag a1 = *(const bfrag*)&Vt[(wr + 16 + li) * ST + kk + quad * 8];
    bfrag b0 = *(const bfrag*)&KbarT[(wc + li) * ST + kk + quad * 8];
    bfrag b1 = *(const bfrag*)&KbarT[(wc + 16 + li) * ST + kk + quad * 8];
    U[0][0] = MFMA16(a0, b0, U[0][0]);
    U[0][1] = MFMA16(a0, b1, U[0][1]);
    U[1][0] = MFMA16(a1, b0, U[1][0]);
    U[1][1] = MFMA16(a1, b1, U[1][1]);
  }

  u16* dst = ut + ((size_t)bid << 12);   // [bh][ch][e][d], bf16
#pragma unroll
  for (int ti = 0; ti < 2; ++ti)
#pragma unroll
    for (int tj = 0; tj < 2; ++tj)
#pragma unroll
      for (int r = 0; r < 4; ++r) {
        int e = wr + ti * 16 + quad * 4 + r;
        int d = wc + tj * 16 + li;
        dst[e * 64 + d] = f2b(U[ti][tj][r]);
      }
}

__global__ __launch_bounds__(256) void k2b_scan(
    const u16* __restrict__ ut, const float* __restrict__ td,
    u16* __restrict__ sbf, float* __restrict__ fstate)
{
  __shared__ float Sl[4 * 65];
  const int tid = threadIdx.x;
  const int bid = blockIdx.x;
  const int bh = bid >> 4, q = bid & 15;       // q: which 256-slice of ed
  const int ed = q * 256 + tid;                // ed = e*64 + d (transposed layout)
  const int h = bh & 15;
  const float Dh = td[h * 64];
  const float DhC = exp2f(64.f * log2f(Dh));

  float S = 0.f;
  size_t idx = ((size_t)bh * 32) * 4096 + ed;
  for (int c = 0; c < 32; ++c, idx += 4096) {
    sbf[idx] = f2b(S);             // state at START of chunk c
    S = S * DhC + b2f(ut[idx]);
  }
  // final state: transpose [e][d] -> [d][e] via LDS
  Sl[(tid >> 6) * 65 + (tid & 63)] = S;   // e = q*4 + (tid>>6), d = tid&63
  __syncthreads();
  int d = tid >> 2, el = tid & 3;
  fstate[(size_t)bh * 4096 + (size_t)d * 64 + q * 4 + el] = Sl[el * 65 + d];
}

__global__ __launch_bounds__(256) void k2c_y(
    const u16* __restrict__ kws, const u16* __restrict__ vws, const u16* __restrict__ rws,
    const u16* __restrict__ sbf, const float* __restrict__ td,
    u16* __restrict__ yws)
{
  __shared__ u16 Rc[64 * ST];     // R natural [t][d]
  __shared__ u16 KcA[64 * ST];    // Ktf natural [s][d]; reused as Abuf [t][s]
  __shared__ u16 Vt[64 * ST];     // V^T [e][s]
  __shared__ u16 STc[64 * ST];    // S^T chunk [e][d]
  __shared__ float Dpow[65];

  const int tid = threadIdx.x;
  const int lane = tid & 63, wave = tid >> 6;
  const int li = lane & 15, quad = lane >> 4;
  const int wr = (wave >> 1) * 32, wc = (wave & 1) * 32;
  const int bid = blockIdx.x;
  const int bh = bid >> 5, ch = bid & 31;
  const int h = bh & 15, bb = bh >> 4;
  const float l2D = log2f(td[h * 64]);
  if (tid <= 64) Dpow[tid] = exp2f((float)tid * l2D);

  const size_t base = (size_t)bh * 131072 + (size_t)ch * 4096;
  const u16* sp = sbf + ((size_t)bid << 12);

#pragma unroll
  for (int it = 0; it < 2; ++it) {
    int c16 = tid + it * 256;
    int row = c16 >> 3, c8 = (c16 & 7) * 8;
    size_t g = base + (size_t)row * 64 + c8;
    *(uint4*)&Rc[row * ST + c8]  = *(const uint4*)(rws + g);
    *(uint4*)&KcA[row * ST + c8] = *(const uint4*)(kws + g);
    *(uint4*)&STc[row * ST + c8] = *(const uint4*)(sp + (size_t)row * 64 + c8);
    uint4 vq = *(const uint4*)(vws + g);
    u16 ve[8]; unpack8(vq, ve);
#pragma unroll
    for (int jj = 0; jj < 8; ++jj) Vt[(c8 + jj) * ST + row] = ve[jj];
  }
  __syncthreads();   // B1

  ffrag P[2][2], Y[2][2];
#pragma unroll
  for (int a = 0; a < 2; ++a)
#pragma unroll
    for (int b = 0; b < 2; ++b)
#pragma unroll
      for (int r = 0; r < 4; ++r) { P[a][b][r] = 0.f; Y[a][b][r] = 0.f; }

#pragma unroll
  for (int kk = 0; kk < 64; kk += 32) {
    bfrag a0 = *(const bfrag*)&Rc[(wr + li) * ST + kk + quad * 8];
    bfrag a1 = *(const bfrag*)&Rc[(wr + 16 + li) * ST + kk + quad * 8];
    bfrag b0 = *(const bfrag*)&KcA[(wc + li) * ST + kk + quad * 8];
    bfrag b1 = *(const bfrag*)&KcA[(wc + 16 + li) * ST + kk + quad * 8];
    P[0][0] = MFMA16(a0, b0, P[0][0]);
    P[0][1] = MFMA16(a0, b1, P[0][1]);
    P[1][0] = MFMA16(a1, b0, P[1][0]);
    P[1][1] = MFMA16(a1, b1, P[1][1]);
    bfrag s0 = *(const bfrag*)&STc[(wc + li) * ST + kk + quad * 8];
    bfrag s1 = *(const bfrag*)&STc[(wc + 16 + li) * ST + kk + quad * 8];
    Y[0][0] = MFMA16(a0, s0, Y[0][0]);
    Y[0][1] = MFMA16(a0, s1, Y[0][1]);
    Y[1][0] = MFMA16(a1, s0, Y[1][0]);
    Y[1][1] = MFMA16(a1, s1, Y[1][1]);
  }

  // row-scale the R@S^T partial by Dh^(t+1) (commutes: scale is per output row)
#pragma unroll
  for (int ti = 0; ti < 2; ++ti)
#pragma unroll
    for (int tj = 0; tj < 2; ++tj)
#pragma unroll
      for (int r = 0; r < 4; ++r) {
        int t = wr + ti * 16 + quad * 4 + r;
        Y[ti][tj][r] *= Dpow[t + 1];
      }
  __syncthreads();   // Bmid: everyone done reading KcA (Ktf)

  // masked decay-scaled A -> Abuf (aliases KcA)
#pragma unroll
  for (int ti = 0; ti < 2; ++ti)
#pragma unroll
    for (int tj = 0; tj < 2; ++tj)
#pragma unroll
      for (int r = 0; r < 4; ++r) {
        int t = wr + ti * 16 + quad * 4 + r;
        int s = wc + tj * 16 + li;
        float v = (t >= s) ? P[ti][tj][r] * Dpow[t - s] : 0.f;
        KcA[t * ST + s] = f2b(v);
      }
  __syncthreads();   // B2: Abuf visible

#pragma unroll
  for (int kk = 0; kk < 64; kk += 32) {
    bfrag aa0 = *(const bfrag*)&KcA[(wr + li) * ST + kk + quad * 8];
    bfrag aa1 = *(const bfrag*)&KcA[(wr + 16 + li) * ST + kk + quad * 8];
    bfrag vb0 = *(const bfrag*)&Vt[(wc + li) * ST + kk + quad * 8];
    bfrag vb1 = *(const bfrag*)&Vt[(wc + 16 + li) * ST + kk + quad * 8];
    Y[0][0] = MFMA16(aa0, vb0, Y[0][0]);
    Y[0][1] = MFMA16(aa0, vb1, Y[0][1]);
    Y[1][0] = MFMA16(aa1, vb0, Y[1][0]);
    Y[1][1] = MFMA16(aa1, vb1, Y[1][1]);
  }

#pragma unroll
  for (int ti = 0; ti < 2; ++ti)
#pragma unroll
    for (int tj = 0; tj < 2; ++tj)
#pragma unroll
      for (int r = 0; r < 4; ++r) {
        int t = wr + ti * 16 + quad * 4 + r;
        int e = wc + tj * 16 + li;
        yws[((size_t)(bb * 2048 + ch * 64 + t)) * 1024 + h * 64 + e] = f2b(Y[ti][tj][r]);
      }
}

// ---------------------------------------------------------------------------
// K3: y = Y_rwkv @ Wo^T, M=8192, N=1024, K=1024.
// Round-4 k1 recipe: BM=256 x BN=128, 512 thr, BK=32 dbuf, GLL16.
// Grid 256 = 1 block/CU exactly; 32 iters/CU (halves barrier count vs 128^2).
// XCD m-window: 4 m-tiles per XCD x 8 n-tiles, m fastest.
// ---------------------------------------------------------------------------
__global__ __launch_bounds__(512, 4) void k3_out(
    const u16* __restrict__ yb, const u16* __restrict__ wob, float* __restrict__ out)
{
  __shared__ u16 As[2][256 * 32];
  __shared__ u16 Bs[2][128 * 32];
  const int tid  = threadIdx.x;
  const int wave = tid >> 6, lane = tid & 63;
  const int li = lane & 15, quad = lane >> 4;
  const int wm = (wave >> 1) * 64, wn = (wave & 1) * 64;

  const int bid = blockIdx.x;
  const int xcd = bid & 7, j = bid >> 3;            // j in [0,32)
  const int n0 = (j >> 2) * 128;                    // 8 n-tiles
  const int m0 = ((xcd << 2) | (j & 3)) * 256;      // 4 m-tiles per XCD

  ffrag acc[4][4];
#pragma unroll
  for (int i = 0; i < 4; ++i)
#pragma unroll
    for (int jj = 0; jj < 4; ++jj)
#pragma unroll
      for (int r = 0; r < 4; ++r) acc[i][jj][r] = 0.f;

  const int sr = lane >> 2, sc = (lane & 3) * 8;
  const u16* ga0 = yb  + (size_t)(m0 + wave * 32 + sr) * 1024 + sc;
  const u16* gb0 = wob + (size_t)(n0 + wave * 16 + sr) * 1024 + sc;

  GLL16(ga0,             As[0] + wave * 1024);
  GLL16(ga0 + 16 * 1024, As[0] + wave * 1024 + 512);
  GLL16(gb0,             Bs[0] + wave * 512);

  for (int it = 0; it < 32; ++it) {
    __syncthreads();
    if (it + 1 < 32) {
      const int nb = (it + 1) & 1;
      const u16* ga = ga0 + (it + 1) * 32;
      const u16* gb = gb0 + (it + 1) * 32;
      GLL16(ga,             As[nb] + wave * 1024);
      GLL16(ga + 16 * 1024, As[nb] + wave * 1024 + 512);
      GLL16(gb,             Bs[nb] + wave * 512);
    }
    const int cb = it & 1;
    bfrag av[4], bv[4];
#pragma unroll
    for (int i = 0; i < 4; ++i)  av[i]  = *(const bfrag*)&As[cb][(wm + i * 16 + li) * 32 + quad * 8];
#pragma unroll
    for (int jj = 0; jj < 4; ++jj) bv[jj] = *(const bfrag*)&Bs[cb][(wn + jj * 16 + li) * 32 + quad * 8];
#pragma unroll
    for (int i = 0; i < 4; ++i)
#pragma unroll
      for (int jj = 0; jj < 4; ++jj)
        acc[i][jj] = MFMA16(av[i], bv[jj], acc[i][jj]);
  }

#pragma unroll
  for (int i = 0; i < 4; ++i)
#pragma unroll
    for (int jj = 0; jj < 4; ++jj)
#pragma unroll
      for (int r = 0; r < 4; ++r) {
        int m = m0 + wm + i * 16 + quad * 4 + r;
        int n = n0 + wn + jj * 16 + li;
        out[(size_t)m * 1024 + n] = acc[i][jj][r];
      }
}

// ---------------------------------------------------------------------------
// Workspace layout (u16 elements):
//   xb   @ 0          (8388608)   -- reused as yws after K1
//   wb   @ 8388608    (3145728)
//   wob  @ 11534336   (1048576)
//   kws  @ 12582912   (8388608)   (B,H,L,HD) k*tf
//   vws  @ 20971520   (8388608)
//   rws  @ 29360128   (8388608)   sigmoid applied
//   ut   @ 37748736   (8388608)   U^T per (bh,chunk), bf16
//   sbf  @ 54525952   (8388608)   S^T per (bh,chunk), bf16
// ---------------------------------------------------------------------------
extern "C" void kernel_launch(void* const* d_in, const int* in_sizes, int n_in,
                              void* d_out, int out_size, void* d_ws, size_t ws_size,
                              hipStream_t stream) {
  const float* x  = (const float*)d_in[0];
  const float* Wk = (const float*)d_in[1];
  const float* Wv = (const float*)d_in[2];
  const float* Wr = (const float*)d_in[3];
  const float* Wo = (const float*)d_in[4];
  const float* td = (const float*)d_in[5];
  const float* tf = (const float*)d_in[6];
  float* out = (float*)d_out;

  u16* ws  = (u16*)d_ws;
  u16* xb  = ws;
  u16* wb  = ws + 8388608;
  u16* wob = ws + 11534336;
  u16* kws = ws + 12582912;
  u16* vws = ws + 20971520;
  u16* rws = ws + 29360128;
  u16* ut  = ws + 37748736;
  u16* sbf = ws + 54525952;
  u16* yws = xb;   // xb dead after K1

  hipLaunchKernelGGL(cvt_all, dim3(12288), dim3(256), 0, stream,
                     x, Wk, Wv, Wr, Wo, xb, wb, wob);
  hipLaunchKernelGGL(k1_proj, dim3(768), dim3(512), 0, stream,
                     xb, wb, tf, kws, vws, rws);
  hipLaunchKernelGGL(k2a_u, dim3(2048), dim3(256), 0, stream,
                     kws, vws, td, ut);
  hipLaunchKernelGGL(k2b_scan, dim3(1024), dim3(256), 0, stream,
                     ut, td, sbf, out + 8388608);
  hipLaunchKernelGGL(k2c_y, dim3(2048), dim3(256), 0, stream,
                     kws, vws, rws, sbf, td, yws);
  hipLaunchKernelGGL(k3_out, dim3(256), dim3(512), 0, stream,
                     yws, wob, out);
}